// Round 3
// baseline (207.866 us; speedup 1.0000x reference)
//
#include <hip/hip_runtime.h>

// Problem constants (from reference setup_inputs)
#define N_TRAIN 4096
#define N_UNL   32768
#define C_DIM   1000
#define G_GRP   512
#define K_MEM   64

#define CE_BLOCKS (N_TRAIN / 16)          // 256 blocks, 16 rows each
#define NBLK      (G_GRP + CE_BLOCKS)     // 768 blocks total

#define CHUNKS  8
#define CCOLS   128                       // fp32 columns per LDS chunk
#define PITCH_B 272                       // LDS row pitch BYTES (128 bf16 + 16 pad; 4-bank stride)
#define ROWS    65                        // 64 members + centroid (no zero rows needed)

typedef short        short8 __attribute__((ext_vector_type(8)));   // 8 bf16 (4 VGPRs)
typedef float        f32x4  __attribute__((ext_vector_type(4)));   // MFMA accumulator
typedef unsigned int u32x2  __attribute__((ext_vector_type(2)));   // 8 B store

// pack two f32 -> two bf16 (round-half-up via +0x8000; inputs ~N(0,1), no overflow risk)
__device__ __forceinline__ unsigned int pack_bf(float a, float b) {
    unsigned int ua = __float_as_uint(a) + 0x8000u;
    unsigned int ub = __float_as_uint(b) + 0x8000u;
    return (ua >> 16) | (ub & 0xffff0000u);
}

// Barrier that does NOT drain vmcnt: LDS writes visible (lgkmcnt(0)) but
// prefetched global loads stay in flight across it.
__device__ __forceinline__ void lds_barrier() {
    asm volatile("s_waitcnt lgkmcnt(0)" ::: "memory");
    __builtin_amdgcn_s_barrier();
}

// ---------------------------------------------------------------------------
// Fused kernel. Blocks 0..511: group path. Gather is wave-per-row: one wave
// reads 1024 B contiguous per row per load (64 lanes x 16 B), one super-chunk
// (256 fp32 cols) at a time; LDS double-buffers 128-col chunks; commit
// alternates half-waves. Centroid via broadcast-B MFMA trick (no zero rows).
// Blocks 512..767: CE path (float4-vectorized).
// ---------------------------------------------------------------------------
__global__ __launch_bounds__(256, 3) void fused_kernel(const float* __restrict__ train,
                                                       const int*   __restrict__ targets,
                                                       const float* __restrict__ unl,
                                                       const int*   __restrict__ cids,
                                                       const int*   __restrict__ mids,
                                                       float* __restrict__ out) {
    __shared__ __align__(16) unsigned short bf[2][ROWS * (PITCH_B / 2)];  // 2 x 17680 B
    __shared__ int   ids_sh[K_MEM];
    __shared__ float sq_sh[K_MEM];
    __shared__ float red_sh[4];
    __shared__ float sqc_sh;

    const int tid  = threadIdx.x;
    const int w    = tid >> 6;
    const int lane = tid & 63;

    if (blockIdx.x >= G_GRP) {
        // ------------------------- CE path -------------------------
        const int blk = (int)blockIdx.x - G_GRP;
        float ce = 0.f;
        for (int r4 = 0; r4 < 4; ++r4) {
            const int row = blk * 16 + w * 4 + r4;
            const float* rp = train + (long)row * C_DIM;
            float4 x[4];
#pragma unroll
            for (int i = 0; i < 4; ++i) {
                const int cb = lane * 4 + i * 256;          // multiple of 4; C_DIM%4==0
                x[i] = (cb < C_DIM) ? *(const float4*)(rp + cb)
                                    : make_float4(-1e30f, -1e30f, -1e30f, -1e30f);
            }
            float m = fmaxf(fmaxf(x[0].x, x[0].y), fmaxf(x[0].z, x[0].w));
#pragma unroll
            for (int i = 1; i < 4; ++i)
                m = fmaxf(m, fmaxf(fmaxf(x[i].x, x[i].y), fmaxf(x[i].z, x[i].w)));
#pragma unroll
            for (int off = 32; off > 0; off >>= 1) m = fmaxf(m, __shfl_xor(m, off, 64));
            float s = 0.f;
#pragma unroll
            for (int i = 0; i < 4; ++i)
                s += __expf(x[i].x - m) + __expf(x[i].y - m) +
                     __expf(x[i].z - m) + __expf(x[i].w - m);
#pragma unroll
            for (int off = 32; off > 0; off >>= 1) s += __shfl_xor(s, off, 64);
            if (lane == 0) {
                int t = targets[row];
                ce += -(rp[t] - m - __logf(s));
            }
        }
        if (lane == 0) red_sh[w] = ce;
        __syncthreads();
        if (tid == 0)
            atomicAdd(out, (red_sh[0] + red_sh[1] + red_sh[2] + red_sh[3]) *
                           (1.0f / (float)N_TRAIN));
        return;
    }

    // ------------------------- group path -------------------------
    const int g    = blockIdx.x;
    const int quad = lane >> 4;
    const int c16  = lane & 15;

    if (tid < K_MEM) ids_sh[tid] = mids[g * K_MEM + tid];
    __syncthreads();

    // Wave w owns member rows w*16+i (i=0..15); wave 3 also owns centroid row 64.
    // Byte offsets fit in u32 (max 32768*4000 < 2^31).
    unsigned int roff[16];
#pragma unroll
    for (int i = 0; i < 16; ++i)
        roff[i] = (unsigned int)ids_sh[w * 16 + i] * (unsigned int)(C_DIM * 4);
    const unsigned int coff = (unsigned int)cids[g] * (unsigned int)(C_DIM * 4);
    const char* const ubase = (const char*)unl;
    const char* const tbase = (const char*)train;

    f32x4 acc[4], accC, accD;
#pragma unroll
    for (int t = 0; t < 4; ++t) acc[t] = (f32x4){0.f, 0.f, 0.f, 0.f};
    accC = (f32x4){0.f, 0.f, 0.f, 0.f};
    accD = (f32x4){0.f, 0.f, 0.f, 0.f};

    const float4 z4 = make_float4(0.f, 0.f, 0.f, 0.f);

    // One register set: a full super-chunk (256 cols) per owned row.
    // Lane l covers fp32 cols sc*256 + l*4 .. +4  (wave-wide 1024 B contiguous).
    float4 regs[16];
    float4 creg;

    {   // super-chunk 0 (cols 0..255 — always valid)
        const long ob = (long)lane * 16;
#pragma unroll
        for (int i = 0; i < 16; ++i)
            regs[i] = *(const float4*)(ubase + roff[i] + ob);
        if (w == 3) creg = *(const float4*)(tbase + coff + ob);
    }

    // Per chunk ch: commit the matching half-wave's registers -> bf[ch&1];
    // after odd commits, refill regs with the next super-chunk (loads cross ONE
    // non-draining barrier in flight). Buffer safety identical to the proven
    // 2-buffer scheme: commit(ch) and MFMA(ch) target the same buffer around
    // one barrier; previous readers of bf[ch&1] (MFMA(ch-2)) are separated by
    // barrier(ch-1). ch is compile-time (full unroll) -> static reg indexing.
#pragma unroll
    for (int ch = 0; ch < CHUNKS; ++ch) {
        unsigned short* const bufp = bf[ch & 1];
        const int l32 = lane & 31;
        if ((ch & 1) == 0 ? (lane < 32) : (lane >= 32)) {
#pragma unroll
            for (int i = 0; i < 16; ++i) {
                u32x2 h = {pack_bf(regs[i].x, regs[i].y), pack_bf(regs[i].z, regs[i].w)};
                *(u32x2*)((char*)bufp + (w * 16 + i) * PITCH_B + l32 * 8) = h;
            }
            if (w == 3) {
                u32x2 h = {pack_bf(creg.x, creg.y), pack_bf(creg.z, creg.w)};
                *(u32x2*)((char*)bufp + 64 * PITCH_B + l32 * 8) = h;
            }
        }
        if ((ch & 1) == 1 && ch + 1 < CHUNKS) {
            const int  sc = (ch + 1) >> 1;              // 1, 2, 3 (compile-time)
            const int  cb = sc * 256 + lane * 4;
            const bool v  = (cb < C_DIM);               // folds away for sc=1,2
            const long ob = (long)cb * 4;
#pragma unroll
            for (int i = 0; i < 16; ++i)
                regs[i] = v ? *(const float4*)(ubase + roff[i] + ob) : z4;
            if (w == 3) creg = v ? *(const float4*)(tbase + coff + ob) : z4;
        }
        lds_barrier();   // LDS visible; prefetched global loads stay in flight
        __builtin_amdgcn_s_setprio(1);
#pragma unroll
        for (int s = 0; s < 4; ++s) {
            const int   kbb  = s * 64 + quad * 16;
            const char* base = (const char*)bufp;
            short8 b0 = *(const short8*)(base + (0 * 16 + c16) * PITCH_B + kbb);
            short8 b1 = *(const short8*)(base + (1 * 16 + c16) * PITCH_B + kbb);
            short8 b2 = *(const short8*)(base + (2 * 16 + c16) * PITCH_B + kbb);
            short8 b3 = *(const short8*)(base + (3 * 16 + c16) * PITCH_B + kbb);
            short8 aM = *(const short8*)(base + (w * 16 + c16) * PITCH_B + kbb);
            short8 bC = *(const short8*)(base + 64 * PITCH_B + kbb);   // broadcast
            acc[0] = __builtin_amdgcn_mfma_f32_16x16x32_bf16(aM, b0, acc[0], 0, 0, 0);
            acc[1] = __builtin_amdgcn_mfma_f32_16x16x32_bf16(aM, b1, acc[1], 0, 0, 0);
            acc[2] = __builtin_amdgcn_mfma_f32_16x16x32_bf16(aM, b2, acc[2], 0, 0, 0);
            acc[3] = __builtin_amdgcn_mfma_f32_16x16x32_bf16(aM, b3, acc[3], 0, 0, 0);
            // every B column == c  =>  accC[r] = m_{w*16+quad*4+r} . c (all c16)
            accC = __builtin_amdgcn_mfma_f32_16x16x32_bf16(aM, bC, accC, 0, 0, 0);
            // every A row == c and every B col == c => accD[*] = ||c||^2
            if (w == 0)
                accD = __builtin_amdgcn_mfma_f32_16x16x32_bf16(bC, bC, accD, 0, 0, 0);
        }
        __builtin_amdgcn_s_setprio(0);
    }

    // ---- gram diagonal -> sq_sh (tile (w,w): i = w*16+quad*4+r, j = w*16+c16) ----
#pragma unroll
    for (int t = 0; t < 4; ++t) {
        if (t == w) {
#pragma unroll
            for (int r = 0; r < 4; ++r)
                if (c16 == quad * 4 + r) sq_sh[w * 16 + c16] = acc[t][r];
        }
    }
    if (tid == 0) sqc_sh = accD[0];        // ||c||^2
    __syncthreads();

    float local = 0.f;
    // align: accC[r] holds m_i.c for i = w*16+quad*4+r (replicated over c16);
    // use the c16==0 copy.
    if (c16 == 0) {
#pragma unroll
        for (int r = 0; r < 4; ++r) {
            const int j = w * 16 + quad * 4 + r;
            const float d2 = sqc_sh + sq_sh[j] - 2.f * accC[r];
            if (d2 > 0.f) local += sqrtf(d2) * (1.0f / (float)N_UNL);    // LAMBDA_1 = 1
        }
    }
    // robust: upper triangle of member gram
#pragma unroll
    for (int t = 0; t < 4; ++t) {
#pragma unroll
        for (int r = 0; r < 4; ++r) {
            const int i = w * 16 + quad * 4 + r;
            const int j = t * 16 + c16;
            if (j > i) {
                const float d2 = sq_sh[i] + sq_sh[j] - 2.f * acc[t][r];
                if (d2 > 0.f)
                    local += sqrtf(d2) * (0.5f / ((float)K_MEM * (float)N_UNL)); // L2=0.5
            }
        }
    }

    // wave shuffle-reduce, then 4 partials across waves
#pragma unroll
    for (int off = 32; off > 0; off >>= 1) local += __shfl_xor(local, off, 64);
    if (lane == 0) red_sh[w] = local;
    __syncthreads();
    if (tid == 0) atomicAdd(out, red_sh[0] + red_sh[1] + red_sh[2] + red_sh[3]);
}

// ---------------------------------------------------------------------------
extern "C" void kernel_launch(void* const* d_in, const int* in_sizes, int n_in,
                              void* d_out, int out_size, void* d_ws, size_t ws_size,
                              hipStream_t stream) {
    (void)in_sizes; (void)n_in; (void)d_ws; (void)ws_size;
    const float* train_logits  = (const float*)d_in[0];
    const int*   train_targets = (const int*)d_in[1];
    const float* unl           = (const float*)d_in[2];
    const int*   centroid_ids  = (const int*)d_in[3];
    const int*   member_ids    = (const int*)d_in[4];
    float* out = (float*)d_out;

    hipMemsetAsync(out, 0, (size_t)out_size * sizeof(float), stream);
    fused_kernel<<<NBLK, 256, 0, stream>>>(train_logits, train_targets, unl,
                                           centroid_ids, member_ids, out);
}

// Round 4
// 204.319 us; speedup vs baseline: 1.0174x; 1.0174x over previous
//
#include <hip/hip_runtime.h>

// Problem constants (from reference setup_inputs)
#define N_TRAIN 4096
#define N_UNL   32768
#define C_DIM   1000
#define G_GRP   512
#define K_MEM   64

#define CE_BLOCKS (N_TRAIN / 16)          // 256 blocks, 16 rows each
#define NBLK      (G_GRP + CE_BLOCKS)     // 768 blocks total

#define CHUNKS  8
#define CCOLS   128                       // fp32 columns per LDS chunk
#define PITCH_B 272                       // LDS row pitch BYTES (128 bf16 + 16 pad; 4-bank stride)
#define ROWS    65                        // 64 members + centroid (no zero rows)

typedef short        short8 __attribute__((ext_vector_type(8)));   // 8 bf16 (4 VGPRs)
typedef float        f32x4  __attribute__((ext_vector_type(4)));   // MFMA accumulator
typedef unsigned int u32x2  __attribute__((ext_vector_type(2)));   // 8 B store

// pack two f32 -> two bf16 (round-half-up via +0x8000; inputs ~N(0,1), no overflow risk)
__device__ __forceinline__ unsigned int pack_bf(float a, float b) {
    unsigned int ua = __float_as_uint(a) + 0x8000u;
    unsigned int ub = __float_as_uint(b) + 0x8000u;
    return (ua >> 16) | (ub & 0xffff0000u);
}

// Barrier that does NOT drain vmcnt: LDS writes visible (lgkmcnt(0)) but
// prefetched global loads stay in flight across it.
__device__ __forceinline__ void lds_barrier() {
    asm volatile("s_waitcnt lgkmcnt(0)" ::: "memory");
    __builtin_amdgcn_s_barrier();
}

// ---------------------------------------------------------------------------
// Fused kernel, occupancy-optimized: single register set (1-deep prefetch),
// u32 row offsets, 65-row LDS double buffer -> ~100 VGPR, 4 blocks/CU.
// Blocks 0..511: group path (gather -> bf16 LDS -> MFMA gram -> align+robust).
// Blocks 512..767: CE path.
// ---------------------------------------------------------------------------
__global__ __launch_bounds__(256, 4) void fused_kernel(const float* __restrict__ train,
                                                       const int*   __restrict__ targets,
                                                       const float* __restrict__ unl,
                                                       const int*   __restrict__ cids,
                                                       const int*   __restrict__ mids,
                                                       float* __restrict__ out) {
    __shared__ __align__(16) unsigned short bf[2][ROWS * (PITCH_B / 2)];  // 2 x 17680 B
    __shared__ int   ids_sh[K_MEM];
    __shared__ float sq_sh[K_MEM];
    __shared__ float red_sh[4];
    __shared__ float sqc_sh;

    const int tid  = threadIdx.x;
    const int w    = tid >> 6;
    const int lane = tid & 63;

    if (blockIdx.x >= G_GRP) {
        // ------------------------- CE path -------------------------
        const int blk = (int)blockIdx.x - G_GRP;
        float ce = 0.f;
        for (int r4 = 0; r4 < 4; ++r4) {
            const int row = blk * 16 + w * 4 + r4;
            const float* rp = train + (long)row * C_DIM;
            float4 x[4];
#pragma unroll
            for (int i = 0; i < 4; ++i) {
                const int cb = lane * 4 + i * 256;          // multiple of 4; C_DIM%4==0
                x[i] = (cb < C_DIM) ? *(const float4*)(rp + cb)
                                    : make_float4(-1e30f, -1e30f, -1e30f, -1e30f);
            }
            float m = fmaxf(fmaxf(x[0].x, x[0].y), fmaxf(x[0].z, x[0].w));
#pragma unroll
            for (int i = 1; i < 4; ++i)
                m = fmaxf(m, fmaxf(fmaxf(x[i].x, x[i].y), fmaxf(x[i].z, x[i].w)));
#pragma unroll
            for (int off = 32; off > 0; off >>= 1) m = fmaxf(m, __shfl_xor(m, off, 64));
            float s = 0.f;
#pragma unroll
            for (int i = 0; i < 4; ++i)
                s += __expf(x[i].x - m) + __expf(x[i].y - m) +
                     __expf(x[i].z - m) + __expf(x[i].w - m);
#pragma unroll
            for (int off = 32; off > 0; off >>= 1) s += __shfl_xor(s, off, 64);
            if (lane == 0) {
                int t = targets[row];
                ce += -(rp[t] - m - __logf(s));
            }
        }
        if (lane == 0) red_sh[w] = ce;
        __syncthreads();
        if (tid == 0)
            atomicAdd(out, (red_sh[0] + red_sh[1] + red_sh[2] + red_sh[3]) *
                           (1.0f / (float)N_TRAIN));
        return;
    }

    // ------------------------- group path -------------------------
    const int g    = blockIdx.x;
    const int quad = lane >> 4;
    const int c16  = lane & 15;

    if (tid < K_MEM) ids_sh[tid] = mids[g * K_MEM + tid];
    __syncthreads();

    // staging map: thread (rgrp,l32) owns rows rgrp+8i (i=0..7), fp32 cols
    // [l32*4, l32*4+4) of each 128-col chunk. u32 byte offsets (max < 2^31).
    const int rgrp = tid >> 5;          // 0..7
    const int l32  = tid & 31;

    unsigned int roff[8];
#pragma unroll
    for (int i = 0; i < 8; ++i)
        roff[i] = (unsigned int)ids_sh[rgrp + 8 * i] * (unsigned int)(C_DIM * 4);
    const unsigned int coff = (unsigned int)cids[g] * (unsigned int)(C_DIM * 4);
    const char* const ubase = (const char*)unl;
    const char* const tbase = (const char*)train;

    f32x4 acc[4], accC, accD;
#pragma unroll
    for (int t = 0; t < 4; ++t) acc[t] = (f32x4){0.f, 0.f, 0.f, 0.f};
    accC = (f32x4){0.f, 0.f, 0.f, 0.f};
    accD = (f32x4){0.f, 0.f, 0.f, 0.f};

    const float4 z4 = make_float4(0.f, 0.f, 0.f, 0.f);

    // Single register set, 1-deep prefetch: loads for chunk ch+1 are issued
    // right after commit(ch) consumes mreg, and stay in flight across the
    // non-draining barrier while MFMA(ch) runs.
    float4 mreg[8];
    float4 creg;
    {   // chunk 0 (cols 0..127 — always valid)
        const unsigned int ob = (unsigned int)(l32 * 16);
#pragma unroll
        for (int i = 0; i < 8; ++i)
            mreg[i] = *(const float4*)(ubase + (size_t)(roff[i] + ob));
        if (tid < 32) creg = *(const float4*)(tbase + (size_t)(coff + ob));
    }

#pragma unroll
    for (int ch = 0; ch < CHUNKS; ++ch) {
        unsigned short* const bufp = bf[ch & 1];
        // ---- commit mreg -> bf16 LDS (full wave active) ----
#pragma unroll
        for (int i = 0; i < 8; ++i) {
            u32x2 h = {pack_bf(mreg[i].x, mreg[i].y), pack_bf(mreg[i].z, mreg[i].w)};
            *(u32x2*)((char*)bufp + (rgrp + 8 * i) * PITCH_B + l32 * 8) = h;
        }
        if (tid < 32) {
            u32x2 h = {pack_bf(creg.x, creg.y), pack_bf(creg.z, creg.w)};
            *(u32x2*)((char*)bufp + 64 * PITCH_B + tid * 8) = h;
        }
        // ---- issue next chunk's loads (land during MFMA below) ----
        if (ch + 1 < CHUNKS) {
            const int  col = (ch + 1) * CCOLS + l32 * 4;
            const bool v   = (col < C_DIM);
            const unsigned int ob = (unsigned int)(col * 4);
#pragma unroll
            for (int i = 0; i < 8; ++i)
                mreg[i] = v ? *(const float4*)(ubase + (size_t)(roff[i] + ob)) : z4;
            if (tid < 32) creg = v ? *(const float4*)(tbase + (size_t)(coff + ob)) : z4;
        }
        lds_barrier();   // LDS visible; prefetched global loads stay in flight
        __builtin_amdgcn_s_setprio(1);
#pragma unroll
        for (int s = 0; s < 4; ++s) {
            const int   kbb  = s * 64 + quad * 16;
            const char* base = (const char*)bufp;
            short8 b0 = *(const short8*)(base + (0 * 16 + c16) * PITCH_B + kbb);
            short8 b1 = *(const short8*)(base + (1 * 16 + c16) * PITCH_B + kbb);
            short8 b2 = *(const short8*)(base + (2 * 16 + c16) * PITCH_B + kbb);
            short8 b3 = *(const short8*)(base + (3 * 16 + c16) * PITCH_B + kbb);
            short8 aM = *(const short8*)(base + (w * 16 + c16) * PITCH_B + kbb);
            short8 bC = *(const short8*)(base + 64 * PITCH_B + kbb);   // broadcast
            acc[0] = __builtin_amdgcn_mfma_f32_16x16x32_bf16(aM, b0, acc[0], 0, 0, 0);
            acc[1] = __builtin_amdgcn_mfma_f32_16x16x32_bf16(aM, b1, acc[1], 0, 0, 0);
            acc[2] = __builtin_amdgcn_mfma_f32_16x16x32_bf16(aM, b2, acc[2], 0, 0, 0);
            acc[3] = __builtin_amdgcn_mfma_f32_16x16x32_bf16(aM, b3, acc[3], 0, 0, 0);
            // every B column == c  =>  accC[r] = m_{w*16+quad*4+r} . c (all c16)
            accC = __builtin_amdgcn_mfma_f32_16x16x32_bf16(aM, bC, accC, 0, 0, 0);
            // every A row == c and every B col == c => accD[*] = ||c||^2
            if (w == 0)
                accD = __builtin_amdgcn_mfma_f32_16x16x32_bf16(bC, bC, accD, 0, 0, 0);
        }
        __builtin_amdgcn_s_setprio(0);
    }

    // ---- gram diagonal -> sq_sh (tile (w,w): i = w*16+quad*4+r, j = w*16+c16) ----
#pragma unroll
    for (int t = 0; t < 4; ++t) {
        if (t == w) {
#pragma unroll
            for (int r = 0; r < 4; ++r)
                if (c16 == quad * 4 + r) sq_sh[w * 16 + c16] = acc[t][r];
        }
    }
    if (tid == 0) sqc_sh = accD[0];        // ||c||^2
    __syncthreads();

    float local = 0.f;
    // align: accC[r] holds m_i.c for i = w*16+quad*4+r (replicated over c16);
    // use the c16==0 copy.
    if (c16 == 0) {
#pragma unroll
        for (int r = 0; r < 4; ++r) {
            const int j = w * 16 + quad * 4 + r;
            const float d2 = sqc_sh + sq_sh[j] - 2.f * accC[r];
            if (d2 > 0.f) local += sqrtf(d2) * (1.0f / (float)N_UNL);    // LAMBDA_1 = 1
        }
    }
    // robust: upper triangle of member gram
#pragma unroll
    for (int t = 0; t < 4; ++t) {
#pragma unroll
        for (int r = 0; r < 4; ++r) {
            const int i = w * 16 + quad * 4 + r;
            const int j = t * 16 + c16;
            if (j > i) {
                const float d2 = sq_sh[i] + sq_sh[j] - 2.f * acc[t][r];
                if (d2 > 0.f)
                    local += sqrtf(d2) * (0.5f / ((float)K_MEM * (float)N_UNL)); // L2=0.5
            }
        }
    }

    // wave shuffle-reduce, then 4 partials across waves
#pragma unroll
    for (int off = 32; off > 0; off >>= 1) local += __shfl_xor(local, off, 64);
    if (lane == 0) red_sh[w] = local;
    __syncthreads();
    if (tid == 0) atomicAdd(out, red_sh[0] + red_sh[1] + red_sh[2] + red_sh[3]);
}

// ---------------------------------------------------------------------------
extern "C" void kernel_launch(void* const* d_in, const int* in_sizes, int n_in,
                              void* d_out, int out_size, void* d_ws, size_t ws_size,
                              hipStream_t stream) {
    (void)in_sizes; (void)n_in; (void)d_ws; (void)ws_size;
    const float* train_logits  = (const float*)d_in[0];
    const int*   train_targets = (const int*)d_in[1];
    const float* unl           = (const float*)d_in[2];
    const int*   centroid_ids  = (const int*)d_in[3];
    const int*   member_ids    = (const int*)d_in[4];
    float* out = (float*)d_out;

    hipMemsetAsync(out, 0, (size_t)out_size * sizeof(float), stream);
    fused_kernel<<<NBLK, 256, 0, stream>>>(train_logits, train_targets, unl,
                                           centroid_ids, member_ids, out);
}